// Round 6
// baseline (309.033 us; speedup 1.0000x reference)
//
#include <hip/hip_runtime.h>
#include <cstdint>
#include <cstddef>

#define NB    16
#define NC    512
#define NHW   576
#define NTF   512
#define NHEAD 8
#define NCPH  64
#define ATT_SCALE 0.125f
#define SCALE_L2E 0.18033688011112042f   // 0.125 * log2(e)

typedef float  floatx4 __attribute__((ext_vector_type(4)));
typedef short  short8  __attribute__((ext_vector_type(8)));
typedef unsigned short ushortx4 __attribute__((ext_vector_type(4)));

__device__ __forceinline__ unsigned short f2bf(float f) {
    unsigned int u = __float_as_uint(f);
    u += 0x7fffu + ((u >> 16) & 1u);
    return (unsigned short)(u >> 16);
}
__device__ __forceinline__ float bf2f(unsigned short h) {
    return __uint_as_float(((unsigned int)h) << 16);
}

// ---------------------------------------------------------------- prep kernels

// Convert weights to bf16. Wqkm = stacked [Wq; Wk; Wm[:, :512]] (1536 x 512).
__global__ void k_prep_weights(const float* __restrict__ Wq, const float* __restrict__ Wk,
                               const float* __restrict__ Wm, const float* __restrict__ Wv,
                               const float* __restrict__ Wr,
                               unsigned short* __restrict__ Wqkm,
                               unsigned short* __restrict__ Wv_bf,
                               unsigned short* __restrict__ Wr_bf) {
    int i = blockIdx.x * 256 + threadIdx.x;   // 0 .. 1536*512 + 2*512*512 - 1 (exact grid)
    if (i < 1536 * 512) {
        int r = i >> 9, c = i & 511;
        float v;
        if (r < 512)       v = Wq[r * 512 + c];
        else if (r < 1024) v = Wk[(r - 512) * 512 + c];
        else               v = Wm[(size_t)(r - 1024) * 1024 + c];
        Wqkm[i] = f2bf(v);
    } else {
        int j = i - 1536 * 512;
        if (j < 512 * 512) Wv_bf[j] = f2bf(Wv[j]);
        else               Wr_bf[j - 512 * 512] = f2bf(Wr[j - 512 * 512]);
    }
}

// xT[b][p][c] = bf16(x[b][c][p])   (tiled 32x32 transpose)
__global__ void k_prep_xT(const float* __restrict__ x, unsigned short* __restrict__ xT) {
    __shared__ float tile[32][33];
    int b  = blockIdx.z;
    int p0 = blockIdx.x * 32, c0 = blockIdx.y * 32;
    int tx = threadIdx.x, ty = threadIdx.y;           // (32, 8)
    const float* xb = x + (size_t)b * NC * NHW;
    #pragma unroll
    for (int k = 0; k < 4; k++)
        tile[ty + k * 8][tx] = xb[(size_t)(c0 + ty + k * 8) * NHW + p0 + tx];
    __syncthreads();
    unsigned short* xTb = xT + (size_t)b * NHW * NC;
    #pragma unroll
    for (int k = 0; k < 4; k++)
        xTb[(size_t)(p0 + ty + k * 8) * NC + c0 + tx] = f2bf(tile[tx][ty + k * 8]);
}

// tm[b][o] = dot(Wt_w[o], t[b]) + Wt_b[o];  tmerge[b][o] = dot(Wm[o][512:], t[b])
__global__ void k_prep_t(const float* __restrict__ t, const float* __restrict__ Wt_w,
                         const float* __restrict__ Wt_b, const float* __restrict__ Wm,
                         float* __restrict__ tm, float* __restrict__ tmerge) {
    __shared__ float ts[512];
    int b = blockIdx.x;
    int tid = threadIdx.x;
    ts[tid]       = t[b * 512 + tid];
    ts[tid + 256] = t[b * 512 + tid + 256];
    __syncthreads();
    int oo = blockIdx.y * 256 + tid;                  // 0..1023
    const float* Wrow = (oo < 512) ? (Wt_w + (size_t)oo * 512)
                                   : (Wm + (size_t)(oo - 512) * 1024 + 512);
    float acc = 0.f;
    #pragma unroll 4
    for (int c = 0; c < 512; c += 4) {
        float4 w = *reinterpret_cast<const float4*>(Wrow + c);
        acc += w.x * ts[c] + w.y * ts[c + 1] + w.z * ts[c + 2] + w.w * ts[c + 3];
    }
    if (oo < 512) tm[b * 512 + oo] = acc + Wt_b[oo];
    else          tmerge[b * 512 + (oo - 512)] = acc;
}

// ---------------------------------------------------------------- GEMM core

// Per-wave 64x64 tile, K=512, A: [M][512] bf16 row-major (K-contig),
// B: [N][512] bf16 row-major (K-contig).  All fragment loads straight from global/L2.
__device__ __forceinline__ void gemm64(const unsigned short* __restrict__ A,
                                       const unsigned short* __restrict__ Bx,
                                       int lane, floatx4 (&acc)[4][4]) {
    int r  = lane & 15;
    int ko = (lane >> 4) * 8;
    const unsigned short* Ap = A  + (size_t)r * NC + ko;
    const unsigned short* Bp = Bx + (size_t)r * NC + ko;
    for (int k0 = 0; k0 < 512; k0 += 32) {
        short8 a[4], bb[4];
        #pragma unroll
        for (int i = 0; i < 4; i++)
            a[i] = *reinterpret_cast<const short8*>(Ap + i * 16 * NC + k0);
        #pragma unroll
        for (int j = 0; j < 4; j++)
            bb[j] = *reinterpret_cast<const short8*>(Bp + j * 16 * NC + k0);
        #pragma unroll
        for (int i = 0; i < 4; i++)
            #pragma unroll
            for (int j = 0; j < 4; j++)
                acc[i][j] = __builtin_amdgcn_mfma_f32_16x16x32_bf16(a[i], bb[j], acc[i][j], 0, 0, 0);
    }
}

// Y = Wqkm @ x_b  -> QT/KT/vlT written transposed [b][p][o], vl gets +tmerge.
__global__ void k_gemm_qkm(const unsigned short* __restrict__ Wqkm,
                           const unsigned short* __restrict__ xT,
                           const float* __restrict__ tmerge,
                           unsigned short* __restrict__ QT,
                           unsigned short* __restrict__ KT,
                           unsigned short* __restrict__ vlT) {
    int lane = threadIdx.x & 63;
    int wid  = threadIdx.x >> 6;
    int tileid = blockIdx.x * 4 + wid;                // 0..215
    int b = blockIdx.y;
    int o0 = (tileid / 9) * 64;
    int p0 = (tileid % 9) * 64;

    floatx4 acc[4][4];
    floatx4 zz = {0.f, 0.f, 0.f, 0.f};
    #pragma unroll
    for (int i = 0; i < 4; i++)
        #pragma unroll
        for (int j = 0; j < 4; j++) acc[i][j] = zz;

    gemm64(Wqkm + (size_t)o0 * NC, xT + ((size_t)b * NHW + p0) * NC, lane, acc);

    unsigned short* Yt;
    int ob;
    bool addm = false;
    if (o0 < 512)       { Yt = QT;  ob = o0; }
    else if (o0 < 1024) { Yt = KT;  ob = o0 - 512; }
    else                { Yt = vlT; ob = o0 - 1024; addm = true; }

    int cl = lane & 15;
    int r0 = (lane >> 4) * 4;
    #pragma unroll
    for (int i = 0; i < 4; i++) {
        int orow = ob + i * 16 + r0;
        float a0 = 0.f, a1 = 0.f, a2 = 0.f, a3 = 0.f;
        if (addm) {
            float4 tv = *reinterpret_cast<const float4*>(tmerge + b * NC + orow);
            a0 = tv.x; a1 = tv.y; a2 = tv.z; a3 = tv.w;
        }
        #pragma unroll
        for (int jn = 0; jn < 4; jn++) {
            int p = p0 + jn * 16 + cl;
            ushortx4 pk;
            pk[0] = f2bf(acc[i][jn][0] + a0);
            pk[1] = f2bf(acc[i][jn][1] + a1);
            pk[2] = f2bf(acc[i][jn][2] + a2);
            pk[3] = f2bf(acc[i][jn][3] + a3);
            *reinterpret_cast<ushortx4*>(Yt + ((size_t)b * NHW + p) * NC + orow) = pk;
        }
    }
}

// V = Wv @ vl, natural layout V[b][o][p] bf16.
__global__ void k_gemm_v(const unsigned short* __restrict__ Wv_bf,
                         const unsigned short* __restrict__ vlT,
                         unsigned short* __restrict__ V) {
    int lane = threadIdx.x & 63;
    int wid  = threadIdx.x >> 6;
    int tileid = blockIdx.x * 4 + wid;                // 0..71
    int b = blockIdx.y;
    int o0 = (tileid / 9) * 64;
    int p0 = (tileid % 9) * 64;

    floatx4 acc[4][4];
    floatx4 zz = {0.f, 0.f, 0.f, 0.f};
    #pragma unroll
    for (int i = 0; i < 4; i++)
        #pragma unroll
        for (int j = 0; j < 4; j++) acc[i][j] = zz;

    gemm64(Wv_bf + (size_t)o0 * NC, vlT + ((size_t)b * NHW + p0) * NC, lane, acc);

    int cl = lane & 15;
    int r0 = (lane >> 4) * 4;
    #pragma unroll
    for (int i = 0; i < 4; i++)
        #pragma unroll
        for (int jn = 0; jn < 4; jn++)
            #pragma unroll
            for (int j = 0; j < 4; j++)
                V[((size_t)b * NC + o0 + i * 16 + r0 + j) * NHW + p0 + jn * 16 + cl] =
                    f2bf(acc[i][jn][j]);
}

// out = Wr @ AO^T + Wr_b, natural layout f32 [b][o][p].
__global__ void k_gemm_final(const unsigned short* __restrict__ Wr_bf,
                             const unsigned short* __restrict__ AO,
                             const float* __restrict__ Wr_b,
                             float* __restrict__ out) {
    int lane = threadIdx.x & 63;
    int wid  = threadIdx.x >> 6;
    int tileid = blockIdx.x * 4 + wid;                // 0..71
    int b = blockIdx.y;
    int o0 = (tileid / 9) * 64;
    int p0 = (tileid % 9) * 64;

    floatx4 acc[4][4];
    floatx4 zz = {0.f, 0.f, 0.f, 0.f};
    #pragma unroll
    for (int i = 0; i < 4; i++)
        #pragma unroll
        for (int j = 0; j < 4; j++) acc[i][j] = zz;

    gemm64(Wr_bf + (size_t)o0 * NC, AO + ((size_t)b * NHW + p0) * NC, lane, acc);

    int cl = lane & 15;
    int r0 = (lane >> 4) * 4;
    #pragma unroll
    for (int i = 0; i < 4; i++) {
        float4 bv = *reinterpret_cast<const float4*>(Wr_b + o0 + i * 16 + r0);
        float bias[4] = {bv.x, bv.y, bv.z, bv.w};
        #pragma unroll
        for (int jn = 0; jn < 4; jn++)
            #pragma unroll
            for (int j = 0; j < 4; j++)
                out[((size_t)b * NC + o0 + i * 16 + r0 + j) * NHW + p0 + jn * 16 + cl] =
                    acc[i][jn][j] + bias[j];
    }
}

// ---------------------------------------------------------------- cross + o2

// Per (b,h): cross[m] = softmax_m( scale * dot(x[b, h*64: , m], tm[b, h*64:]) )
//            o2[b,h,c] = sum_m V[b][h*64+c][m] * cross[m]
__global__ void k_cross_o2(const unsigned short* __restrict__ xT,
                           const unsigned short* __restrict__ V,
                           const float* __restrict__ tm,
                           float* __restrict__ o2) {
    __shared__ float tms[64];
    __shared__ float ss[576];
    __shared__ float red[8];
    __shared__ float part[4][64];
    int bh = blockIdx.x;
    int b = bh >> 3, h = bh & 7;
    int tid = threadIdx.x;

    if (tid < 64) tms[tid] = tm[b * 512 + h * 64 + tid];
    __syncthreads();

    for (int m = tid; m < 576; m += 256) {
        const short8* xr8 = reinterpret_cast<const short8*>(xT + ((size_t)b * NHW + m) * NC + h * 64);
        float acc = 0.f;
        #pragma unroll
        for (int cc = 0; cc < 8; cc++) {
            short8 v8 = xr8[cc];
            #pragma unroll
            for (int q = 0; q < 8; q++)
                acc += bf2f((unsigned short)v8[q]) * tms[cc * 8 + q];
        }
        ss[m] = acc * ATT_SCALE;
    }
    __syncthreads();

    float pmax = -3e38f;
    for (int m = tid; m < 576; m += 256) pmax = fmaxf(pmax, ss[m]);
    #pragma unroll
    for (int off = 32; off; off >>= 1) pmax = fmaxf(pmax, __shfl_xor(pmax, off));
    if ((tid & 63) == 0) red[tid >> 6] = pmax;
    __syncthreads();
    float mx = fmaxf(fmaxf(red[0], red[1]), fmaxf(red[2], red[3]));

    float psum = 0.f;
    for (int m = tid; m < 576; m += 256) {
        float e = __expf(ss[m] - mx);
        ss[m] = e;
        psum += e;
    }
    #pragma unroll
    for (int off = 32; off; off >>= 1) psum += __shfl_xor(psum, off);
    if ((tid & 63) == 0) red[4 + (tid >> 6)] = psum;
    __syncthreads();
    float inv = 1.f / (red[4] + red[5] + red[6] + red[7]);

    int c = tid & 63, seg = tid >> 6;
    const unsigned short* vr = V + ((size_t)b * NC + h * 64 + c) * NHW;
    float pa = 0.f;
    for (int m = seg * 144; m < seg * 144 + 144; m++) pa += bf2f(vr[m]) * ss[m];
    part[seg][c] = pa;
    __syncthreads();
    if (tid < 64)
        o2[(b * 8 + h) * 64 + tid] =
            (part[0][tid] + part[1][tid] + part[2][tid] + part[3][tid]) * inv;
}

// ---------------------------------------------------------------- attention core

// Fused streaming attention, software-pipelined. One wave = 16 query rows of one (b,h).
// XCD-aware decode keeps each bh's K/V on one XCD's L2 (2.6 MB/XCD).
// 64-key chunks; K prefetched one iteration ahead (register dbuf); V issued at
// iteration start, consumed at end; parity-double-buffered LDS bounce for the
// P D->A layout fix-up. No max-subtraction (|S*scale| small, softmax shift-inv).
__global__ void k_attn(const unsigned short* __restrict__ QT,
                       const unsigned short* __restrict__ KT,
                       const unsigned short* __restrict__ V,
                       const float* __restrict__ o2,
                       unsigned short* __restrict__ AO) {
    __shared__ unsigned short pbuf[4][2][16][72];   // [wave][parity][qrow][64 keys + pad]
    int tid  = threadIdx.x;
    int lane = tid & 63, wid = tid >> 6;

    // XCD-grouping decode: bid = xcd + 8*slot; bh = xcd*16 + slot/9; qt = slot%9
    int bid  = blockIdx.x;                // 0..1151
    int xcd  = bid & 7;
    int slot = bid >> 3;                  // 0..143
    int bh   = xcd * 16 + slot / 9;       // all 9 q-tiles of bh share xcd
    int qt   = slot % 9;
    int b = bh >> 3, h = bh & 7;
    int n0 = qt * 64 + wid * 16;
    int cl = lane & 15;
    int r0 = (lane >> 4) * 4;
    int ko = (lane >> 4) * 8;

    const unsigned short* Qb = QT + ((size_t)b * NHW + n0) * NC + h * 64;
    const unsigned short* Kp = KT + (size_t)b * NHW * NC + h * 64 + (size_t)cl * NC + ko;
    const unsigned short* Vp = V  + ((size_t)b * NC + h * 64) * NHW + ko;

    short8 aq0 = *reinterpret_cast<const short8*>(Qb + (size_t)cl * NC + ko);
    short8 aq1 = *reinterpret_cast<const short8*>(Qb + (size_t)cl * NC + 32 + ko);

    floatx4 zz = {0.f, 0.f, 0.f, 0.f};
    floatx4 oacc[4] = {zz, zz, zz, zz};
    float es[4] = {0.f, 0.f, 0.f, 0.f};

    short8 kc[8], kn[8], vv[8];
    // prologue: K for chunk 0
    #pragma unroll
    for (int t = 0; t < 4; t++) {
        kc[2 * t]     = *reinterpret_cast<const short8*>(Kp + (size_t)(t * 16) * NC);
        kc[2 * t + 1] = *reinterpret_cast<const short8*>(Kp + (size_t)(t * 16) * NC + 32);
    }

    #pragma unroll
    for (int chk = 0; chk < 9; chk++) {
        int m0 = chk * 64;
        // prefetch next chunk's K (one full iteration of cover)
        if (chk < 8) {
            #pragma unroll
            for (int t = 0; t < 4; t++) {
                kn[2 * t]     = *reinterpret_cast<const short8*>(Kp + (size_t)(m0 + 64 + t * 16) * NC);
                kn[2 * t + 1] = *reinterpret_cast<const short8*>(Kp + (size_t)(m0 + 64 + t * 16) * NC + 32);
            }
        }
        // V for this chunk (consumed at iteration end; QK+exp+LDS covers latency)
        #pragma unroll
        for (int ct = 0; ct < 4; ct++) {
            vv[2 * ct]     = *reinterpret_cast<const short8*>(Vp + (size_t)(ct * 16 + cl) * NHW + m0);
            vv[2 * ct + 1] = *reinterpret_cast<const short8*>(Vp + (size_t)(ct * 16 + cl) * NHW + m0 + 32);
        }
        // QK^T: 4 independent 16-key S fragments
        floatx4 s[4];
        #pragma unroll
        for (int t = 0; t < 4; t++) {
            s[t] = __builtin_amdgcn_mfma_f32_16x16x32_bf16(aq0, kc[2 * t], zz, 0, 0, 0);
            s[t] = __builtin_amdgcn_mfma_f32_16x16x32_bf16(aq1, kc[2 * t + 1], s[t], 0, 0, 0);
        }
        // P = exp(S*scale); row-sum partials; stage D->A layout in parity LDS buffer
        int par = chk & 1;
        #pragma unroll
        for (int t = 0; t < 4; t++)
            #pragma unroll
            for (int j = 0; j < 4; j++) {
                float e = exp2f(s[t][j] * SCALE_L2E);
                es[j] += e;
                pbuf[wid][par][r0 + j][t * 16 + cl] = f2bf(e);
            }
        short8 pa0 = *reinterpret_cast<const short8*>(&pbuf[wid][par][cl][ko]);
        short8 pa1 = *reinterpret_cast<const short8*>(&pbuf[wid][par][cl][32 + ko]);
        #pragma unroll
        for (int ct = 0; ct < 4; ct++) {
            oacc[ct] = __builtin_amdgcn_mfma_f32_16x16x32_bf16(pa0, vv[2 * ct], oacc[ct], 0, 0, 0);
            oacc[ct] = __builtin_amdgcn_mfma_f32_16x16x32_bf16(pa1, vv[2 * ct + 1], oacc[ct], 0, 0, 0);
        }
        // rotate prefetch registers
        #pragma unroll
        for (int q = 0; q < 8; q++) kc[q] = kn[q];
    }

    // row-sum reduce across the 16-lane column groups
    #pragma unroll
    for (int off = 1; off < 16; off <<= 1)
        #pragma unroll
        for (int j = 0; j < 4; j++) es[j] += __shfl_xor(es[j], off);
    float ri[4];
    #pragma unroll
    for (int j = 0; j < 4; j++) ri[j] = 1.f / es[j];

    // epilogue: normalize, add rank-1 cross term, transpose via LDS, 16B stores
    const float* o2b = o2 + bh * 64;
    #pragma unroll
    for (int ct = 0; ct < 4; ct++) {
        float o2v = o2b[ct * 16 + cl];
        #pragma unroll
        for (int j = 0; j < 4; j++)
            pbuf[wid][0][r0 + j][ct * 16 + cl] = f2bf(oacc[ct][j] * ri[j] + o2v);
    }
    int part = lane >> 4;
    short8 w0 = *reinterpret_cast<const short8*>(&pbuf[wid][0][cl][part * 16]);
    short8 w1 = *reinterpret_cast<const short8*>(&pbuf[wid][0][cl][part * 16 + 8]);
    unsigned short* dst = AO + ((size_t)b * NHW + n0 + cl) * NC + h * 64 + part * 16;
    *reinterpret_cast<short8*>(dst)     = w0;
    *reinterpret_cast<short8*>(dst + 8) = w1;
}

// ---------------------------------------------------------------- launcher

extern "C" void kernel_launch(void* const* d_in, const int* in_sizes, int n_in,
                              void* d_out, int out_size, void* d_ws, size_t ws_size,
                              hipStream_t stream) {
    const float* x    = (const float*)d_in[0];
    const float* t    = (const float*)d_in[1];
    const float* Wk   = (const float*)d_in[2];
    const float* Wq   = (const float*)d_in[3];
    const float* Wt_w = (const float*)d_in[4];
    const float* Wt_b = (const float*)d_in[5];
    const float* Wm   = (const float*)d_in[6];
    const float* Wv   = (const float*)d_in[7];
    const float* Wr_w = (const float*)d_in[8];
    const float* Wr_b = (const float*)d_in[9];
    float* out = (float*)d_out;
    char* ws = (char*)d_ws;

    const size_t SZ_ACT = (size_t)NB * NHW * NC * 2;   // 9437184 bytes
    unsigned short* xT    = (unsigned short*)(ws);
    unsigned short* Wqkm  = (unsigned short*)(ws + 9437184);
    unsigned short* Wv_bf = (unsigned short*)(ws + 11010048);
    unsigned short* Wr_bf = (unsigned short*)(ws + 11534336);
    float*          tm     = (float*)(ws + 12058624);
    float*          tmerge = (float*)(ws + 12091392);
    unsigned short* QT    = (unsigned short*)(ws + 12124160);
    unsigned short* KT    = (unsigned short*)(ws + 21561344);
    unsigned short* vlT   = (unsigned short*)(ws + 30998528);
    unsigned short* Vv    = (unsigned short*)(ws + 40435712);
    float*          o2    = (float*)(ws + 49872896);
    unsigned short* AO    = xT;   // xT is dead after k_cross_o2; alias for AO
    (void)SZ_ACT; (void)in_sizes; (void)n_in; (void)out_size; (void)ws_size;

    k_prep_weights<<<5120, 256, 0, stream>>>(Wq, Wk, Wm, Wv, Wr_w, Wqkm, Wv_bf, Wr_bf);
    k_prep_xT<<<dim3(18, 16, 16), dim3(32, 8), 0, stream>>>(x, xT);
    k_prep_t<<<dim3(16, 4), 256, 0, stream>>>(t, Wt_w, Wt_b, Wm, tm, tmerge);
    k_gemm_qkm<<<dim3(54, 16), 256, 0, stream>>>(Wqkm, xT, tmerge, QT, KT, vlT);
    k_gemm_v<<<dim3(18, 16), 256, 0, stream>>>(Wv_bf, vlT, Vv);
    k_cross_o2<<<128, 256, 0, stream>>>(xT, Vv, tm, o2);
    k_attn<<<1152, 256, 0, stream>>>(QT, KT, Vv, o2, AO);
    k_gemm_final<<<dim3(18, 16), 256, 0, stream>>>(Wr_bf, AO, Wr_b, out);
}

// Round 7
// 208.266 us; speedup vs baseline: 1.4838x; 1.4838x over previous
//
#include <hip/hip_runtime.h>
#include <cstdint>
#include <cstddef>

#define NB    16
#define NC    512
#define NHW   576
#define NTF   512
#define NHEAD 8
#define NCPH  64
#define ATT_SCALE 0.125f
#define SCALE_L2E 0.18033688011112042f   // 0.125 * log2(e)

typedef float  floatx4 __attribute__((ext_vector_type(4)));
typedef short  short8  __attribute__((ext_vector_type(8)));
typedef unsigned short ushortx4 __attribute__((ext_vector_type(4)));

__device__ __forceinline__ unsigned short f2bf(float f) {
    unsigned int u = __float_as_uint(f);
    u += 0x7fffu + ((u >> 16) & 1u);
    return (unsigned short)(u >> 16);
}
__device__ __forceinline__ float bf2f(unsigned short h) {
    return __uint_as_float(((unsigned int)h) << 16);
}

// ---------------------------------------------------------------- prep kernels

// Convert weights to bf16. Wqkm = stacked [Wq; Wk; Wm[:, :512]] (1536 x 512).
__global__ void k_prep_weights(const float* __restrict__ Wq, const float* __restrict__ Wk,
                               const float* __restrict__ Wm, const float* __restrict__ Wv,
                               const float* __restrict__ Wr,
                               unsigned short* __restrict__ Wqkm,
                               unsigned short* __restrict__ Wv_bf,
                               unsigned short* __restrict__ Wr_bf) {
    int i = blockIdx.x * 256 + threadIdx.x;   // 0 .. 1536*512 + 2*512*512 - 1 (exact grid)
    if (i < 1536 * 512) {
        int r = i >> 9, c = i & 511;
        float v;
        if (r < 512)       v = Wq[r * 512 + c];
        else if (r < 1024) v = Wk[(r - 512) * 512 + c];
        else               v = Wm[(size_t)(r - 1024) * 1024 + c];
        Wqkm[i] = f2bf(v);
    } else {
        int j = i - 1536 * 512;
        if (j < 512 * 512) Wv_bf[j] = f2bf(Wv[j]);
        else               Wr_bf[j - 512 * 512] = f2bf(Wr[j - 512 * 512]);
    }
}

// xT[b][p][c] = bf16(x[b][c][p])   (tiled 32x32 transpose)
__global__ void k_prep_xT(const float* __restrict__ x, unsigned short* __restrict__ xT) {
    __shared__ float tile[32][33];
    int b  = blockIdx.z;
    int p0 = blockIdx.x * 32, c0 = blockIdx.y * 32;
    int tx = threadIdx.x, ty = threadIdx.y;           // (32, 8)
    const float* xb = x + (size_t)b * NC * NHW;
    #pragma unroll
    for (int k = 0; k < 4; k++)
        tile[ty + k * 8][tx] = xb[(size_t)(c0 + ty + k * 8) * NHW + p0 + tx];
    __syncthreads();
    unsigned short* xTb = xT + (size_t)b * NHW * NC;
    #pragma unroll
    for (int k = 0; k < 4; k++)
        xTb[(size_t)(p0 + ty + k * 8) * NC + c0 + tx] = f2bf(tile[tx][ty + k * 8]);
}

// tm[b][o] = dot(Wt_w[o], t[b]) + Wt_b[o];  tmerge[b][o] = dot(Wm[o][512:], t[b])
__global__ void k_prep_t(const float* __restrict__ t, const float* __restrict__ Wt_w,
                         const float* __restrict__ Wt_b, const float* __restrict__ Wm,
                         float* __restrict__ tm, float* __restrict__ tmerge) {
    __shared__ float ts[512];
    int b = blockIdx.x;
    int tid = threadIdx.x;
    ts[tid]       = t[b * 512 + tid];
    ts[tid + 256] = t[b * 512 + tid + 256];
    __syncthreads();
    int oo = blockIdx.y * 256 + tid;                  // 0..1023
    const float* Wrow = (oo < 512) ? (Wt_w + (size_t)oo * 512)
                                   : (Wm + (size_t)(oo - 512) * 1024 + 512);
    float acc = 0.f;
    #pragma unroll 4
    for (int c = 0; c < 512; c += 4) {
        float4 w = *reinterpret_cast<const float4*>(Wrow + c);
        acc += w.x * ts[c] + w.y * ts[c + 1] + w.z * ts[c + 2] + w.w * ts[c + 3];
    }
    if (oo < 512) tm[b * 512 + oo] = acc + Wt_b[oo];
    else          tmerge[b * 512 + (oo - 512)] = acc;
}

// ---------------------------------------------------------------- GEMM core

// Per-wave 64x64 tile, K=512, A: [M][512] bf16 row-major (K-contig),
// B: [N][512] bf16 row-major (K-contig).  All fragment loads straight from global/L2.
__device__ __forceinline__ void gemm64(const unsigned short* __restrict__ A,
                                       const unsigned short* __restrict__ Bx,
                                       int lane, floatx4 (&acc)[4][4]) {
    int r  = lane & 15;
    int ko = (lane >> 4) * 8;
    const unsigned short* Ap = A  + (size_t)r * NC + ko;
    const unsigned short* Bp = Bx + (size_t)r * NC + ko;
    for (int k0 = 0; k0 < 512; k0 += 32) {
        short8 a[4], bb[4];
        #pragma unroll
        for (int i = 0; i < 4; i++)
            a[i] = *reinterpret_cast<const short8*>(Ap + i * 16 * NC + k0);
        #pragma unroll
        for (int j = 0; j < 4; j++)
            bb[j] = *reinterpret_cast<const short8*>(Bp + j * 16 * NC + k0);
        #pragma unroll
        for (int i = 0; i < 4; i++)
            #pragma unroll
            for (int j = 0; j < 4; j++)
                acc[i][j] = __builtin_amdgcn_mfma_f32_16x16x32_bf16(a[i], bb[j], acc[i][j], 0, 0, 0);
    }
}

// Y = Wqkm @ x_b  -> QT/KT/vlT written transposed [b][p][o], vl gets +tmerge.
__global__ void k_gemm_qkm(const unsigned short* __restrict__ Wqkm,
                           const unsigned short* __restrict__ xT,
                           const float* __restrict__ tmerge,
                           unsigned short* __restrict__ QT,
                           unsigned short* __restrict__ KT,
                           unsigned short* __restrict__ vlT) {
    int lane = threadIdx.x & 63;
    int wid  = threadIdx.x >> 6;
    int tileid = blockIdx.x * 4 + wid;                // 0..215
    int b = blockIdx.y;
    int o0 = (tileid / 9) * 64;
    int p0 = (tileid % 9) * 64;

    floatx4 acc[4][4];
    floatx4 zz = {0.f, 0.f, 0.f, 0.f};
    #pragma unroll
    for (int i = 0; i < 4; i++)
        #pragma unroll
        for (int j = 0; j < 4; j++) acc[i][j] = zz;

    gemm64(Wqkm + (size_t)o0 * NC, xT + ((size_t)b * NHW + p0) * NC, lane, acc);

    unsigned short* Yt;
    int ob;
    bool addm = false;
    if (o0 < 512)       { Yt = QT;  ob = o0; }
    else if (o0 < 1024) { Yt = KT;  ob = o0 - 512; }
    else                { Yt = vlT; ob = o0 - 1024; addm = true; }

    int cl = lane & 15;
    int r0 = (lane >> 4) * 4;
    #pragma unroll
    for (int i = 0; i < 4; i++) {
        int orow = ob + i * 16 + r0;
        float a0 = 0.f, a1 = 0.f, a2 = 0.f, a3 = 0.f;
        if (addm) {
            float4 tv = *reinterpret_cast<const float4*>(tmerge + b * NC + orow);
            a0 = tv.x; a1 = tv.y; a2 = tv.z; a3 = tv.w;
        }
        #pragma unroll
        for (int jn = 0; jn < 4; jn++) {
            int p = p0 + jn * 16 + cl;
            ushortx4 pk;
            pk[0] = f2bf(acc[i][jn][0] + a0);
            pk[1] = f2bf(acc[i][jn][1] + a1);
            pk[2] = f2bf(acc[i][jn][2] + a2);
            pk[3] = f2bf(acc[i][jn][3] + a3);
            *reinterpret_cast<ushortx4*>(Yt + ((size_t)b * NHW + p) * NC + orow) = pk;
        }
    }
}

// V = Wv @ vl, natural layout V[b][o][p] bf16.
__global__ void k_gemm_v(const unsigned short* __restrict__ Wv_bf,
                         const unsigned short* __restrict__ vlT,
                         unsigned short* __restrict__ V) {
    int lane = threadIdx.x & 63;
    int wid  = threadIdx.x >> 6;
    int tileid = blockIdx.x * 4 + wid;                // 0..71
    int b = blockIdx.y;
    int o0 = (tileid / 9) * 64;
    int p0 = (tileid % 9) * 64;

    floatx4 acc[4][4];
    floatx4 zz = {0.f, 0.f, 0.f, 0.f};
    #pragma unroll
    for (int i = 0; i < 4; i++)
        #pragma unroll
        for (int j = 0; j < 4; j++) acc[i][j] = zz;

    gemm64(Wv_bf + (size_t)o0 * NC, vlT + ((size_t)b * NHW + p0) * NC, lane, acc);

    int cl = lane & 15;
    int r0 = (lane >> 4) * 4;
    #pragma unroll
    for (int i = 0; i < 4; i++)
        #pragma unroll
        for (int jn = 0; jn < 4; jn++)
            #pragma unroll
            for (int j = 0; j < 4; j++)
                V[((size_t)b * NC + o0 + i * 16 + r0 + j) * NHW + p0 + jn * 16 + cl] =
                    f2bf(acc[i][jn][j]);
}

// out = Wr @ AO^T + Wr_b, natural layout f32 [b][o][p].
__global__ void k_gemm_final(const unsigned short* __restrict__ Wr_bf,
                             const unsigned short* __restrict__ AO,
                             const float* __restrict__ Wr_b,
                             float* __restrict__ out) {
    int lane = threadIdx.x & 63;
    int wid  = threadIdx.x >> 6;
    int tileid = blockIdx.x * 4 + wid;                // 0..71
    int b = blockIdx.y;
    int o0 = (tileid / 9) * 64;
    int p0 = (tileid % 9) * 64;

    floatx4 acc[4][4];
    floatx4 zz = {0.f, 0.f, 0.f, 0.f};
    #pragma unroll
    for (int i = 0; i < 4; i++)
        #pragma unroll
        for (int j = 0; j < 4; j++) acc[i][j] = zz;

    gemm64(Wr_bf + (size_t)o0 * NC, AO + ((size_t)b * NHW + p0) * NC, lane, acc);

    int cl = lane & 15;
    int r0 = (lane >> 4) * 4;
    #pragma unroll
    for (int i = 0; i < 4; i++) {
        float4 bv = *reinterpret_cast<const float4*>(Wr_b + o0 + i * 16 + r0);
        float bias[4] = {bv.x, bv.y, bv.z, bv.w};
        #pragma unroll
        for (int jn = 0; jn < 4; jn++)
            #pragma unroll
            for (int j = 0; j < 4; j++)
                out[((size_t)b * NC + o0 + i * 16 + r0 + j) * NHW + p0 + jn * 16 + cl] =
                    acc[i][jn][j] + bias[j];
    }
}

// ---------------------------------------------------------------- cross + o2

// Per (b,h): cross[m] = softmax_m( scale * dot(x[b, h*64: , m], tm[b, h*64:]) )
//            o2[b,h,c] = sum_m V[b][h*64+c][m] * cross[m]
__global__ void k_cross_o2(const unsigned short* __restrict__ xT,
                           const unsigned short* __restrict__ V,
                           const float* __restrict__ tm,
                           float* __restrict__ o2) {
    __shared__ float tms[64];
    __shared__ float ss[576];
    __shared__ float red[8];
    __shared__ float part[4][64];
    int bh = blockIdx.x;
    int b = bh >> 3, h = bh & 7;
    int tid = threadIdx.x;

    if (tid < 64) tms[tid] = tm[b * 512 + h * 64 + tid];
    __syncthreads();

    for (int m = tid; m < 576; m += 256) {
        const short8* xr8 = reinterpret_cast<const short8*>(xT + ((size_t)b * NHW + m) * NC + h * 64);
        float acc = 0.f;
        #pragma unroll
        for (int cc = 0; cc < 8; cc++) {
            short8 v8 = xr8[cc];
            #pragma unroll
            for (int q = 0; q < 8; q++)
                acc += bf2f((unsigned short)v8[q]) * tms[cc * 8 + q];
        }
        ss[m] = acc * ATT_SCALE;
    }
    __syncthreads();

    float pmax = -3e38f;
    for (int m = tid; m < 576; m += 256) pmax = fmaxf(pmax, ss[m]);
    #pragma unroll
    for (int off = 32; off; off >>= 1) pmax = fmaxf(pmax, __shfl_xor(pmax, off));
    if ((tid & 63) == 0) red[tid >> 6] = pmax;
    __syncthreads();
    float mx = fmaxf(fmaxf(red[0], red[1]), fmaxf(red[2], red[3]));

    float psum = 0.f;
    for (int m = tid; m < 576; m += 256) {
        float e = __expf(ss[m] - mx);
        ss[m] = e;
        psum += e;
    }
    #pragma unroll
    for (int off = 32; off; off >>= 1) psum += __shfl_xor(psum, off);
    if ((tid & 63) == 0) red[4 + (tid >> 6)] = psum;
    __syncthreads();
    float inv = 1.f / (red[4] + red[5] + red[6] + red[7]);

    int c = tid & 63, seg = tid >> 6;
    const unsigned short* vr = V + ((size_t)b * NC + h * 64 + c) * NHW;
    float pa = 0.f;
    for (int m = seg * 144; m < seg * 144 + 144; m++) pa += bf2f(vr[m]) * ss[m];
    part[seg][c] = pa;
    __syncthreads();
    if (tid < 64)
        o2[(b * 8 + h) * 64 + tid] =
            (part[0][tid] + part[1][tid] + part[2][tid] + part[3][tid]) * inv;
}

// ---------------------------------------------------------------- attention core

// Fused streaming attention, cooperative-LDS 2-phase pipeline.
// Block = 4 waves = one (bh, qt): 64 query rows. Per 64-key tile all waves
// cooperatively stage K(64x64) and V(64x64) bf16 tiles into double-buffered LDS
// via global_load_lds (width 16, no VGPR round-trip). Source addresses are
// XOR-pre-swizzled (col16 ^= row&7) so the linear LDS dest + swizzled ds_read
// is bank-conflict-free (Guideline 4/21). Pipeline: STAGE(next) -> compute(cur)
// -> barrier (2-phase T3 recipe). No max-subtraction (softmax shift-invariant,
// |S*scale| small).
__global__ void k_attn(const unsigned short* __restrict__ QT,
                       const unsigned short* __restrict__ KT,
                       const unsigned short* __restrict__ V,
                       const float* __restrict__ o2,
                       unsigned short* __restrict__ AO) {
    __shared__ unsigned short Ktile[2][64][64];
    __shared__ unsigned short Vtile[2][64][64];
    __shared__ unsigned short pbuf[4][16][88];   // 176B rows: 16B-aligned, ~2-way banks
    int tid  = threadIdx.x;
    int lane = tid & 63, wid = tid >> 6;

    // XCD-grouping decode: bid = xcd + 8*slot; bh = xcd*16 + slot/9; qt = slot%9
    int bid  = blockIdx.x;                // 0..1151
    int xcd  = bid & 7;
    int slot = bid >> 3;                  // 0..143
    int bh   = xcd * 16 + slot / 9;       // all 9 q-tiles of bh share xcd
    int qt   = slot % 9;
    int b = bh >> 3, h = bh & 7;
    int n0 = qt * 64 + wid * 16;
    int cl = lane & 15;
    int r0 = (lane >> 4) * 4;
    int part = lane >> 4;                 // 0..3
    int ko = part * 8;

    const unsigned short* Qb = QT + ((size_t)b * NHW + n0) * NC + h * 64;
    const unsigned short* Kb = KT + (size_t)b * NHW * NC + h * 64;   // row stride NC
    const unsigned short* Vb = V  + ((size_t)b * NC + h * 64) * NHW; // row stride NHW

    short8 aq0 = *reinterpret_cast<const short8*>(Qb + (size_t)cl * NC + ko);
    short8 aq1 = *reinterpret_cast<const short8*>(Qb + (size_t)cl * NC + 32 + ko);

    // staging lane mapping: covers 8 rows x 128B per instruction
    int srow = lane >> 3;                 // 0..7 (also row&7 for swizzle)
    int scol = (lane & 7) ^ srow;         // XOR-pre-swizzled source 16B slot

    floatx4 zz = {0.f, 0.f, 0.f, 0.f};
    floatx4 oacc[4] = {zz, zz, zz, zz};
    float es[4] = {0.f, 0.f, 0.f, 0.f};

    // ---- prologue: stage tile 0 into buffer 0
    {
        const unsigned short* ks = Kb + (size_t)(wid * 16 + srow) * NC + scol * 8;
        const unsigned short* vs = Vb + (size_t)(wid * 16 + srow) * NHW + scol * 8;
        #pragma unroll
        for (int i = 0; i < 2; i++) {
            __builtin_amdgcn_global_load_lds(
                (const __attribute__((address_space(1))) unsigned int*)(ks + (size_t)i * 8 * NC),
                (__attribute__((address_space(3))) unsigned int*)&Ktile[0][wid * 16 + i * 8][0], 16, 0, 0);
            __builtin_amdgcn_global_load_lds(
                (const __attribute__((address_space(1))) unsigned int*)(vs + (size_t)i * 8 * NHW),
                (__attribute__((address_space(3))) unsigned int*)&Vtile[0][wid * 16 + i * 8][0], 16, 0, 0);
        }
    }
    __syncthreads();

    int buf = 0;
    for (int chk = 0; chk < 9; chk++) {
        int m0 = chk * 64;
        // ---- stage next tile into buf^1 (latency hides under this tile's compute)
        if (chk < 8) {
            const unsigned short* ks = Kb + (size_t)(m0 + 64 + wid * 16 + srow) * NC + scol * 8;
            const unsigned short* vs = Vb + (size_t)(wid * 16 + srow) * NHW + (m0 + 64) + scol * 8;
            #pragma unroll
            for (int i = 0; i < 2; i++) {
                __builtin_amdgcn_global_load_lds(
                    (const __attribute__((address_space(1))) unsigned int*)(ks + (size_t)i * 8 * NC),
                    (__attribute__((address_space(3))) unsigned int*)&Ktile[buf ^ 1][wid * 16 + i * 8][0], 16, 0, 0);
                __builtin_amdgcn_global_load_lds(
                    (const __attribute__((address_space(1))) unsigned int*)(vs + (size_t)i * 8 * NHW),
                    (__attribute__((address_space(3))) unsigned int*)&Vtile[buf ^ 1][wid * 16 + i * 8][0], 16, 0, 0);
            }
        }

        // ---- QK^T from swizzled K tile: 4 independent 16-key S fragments
        floatx4 s[4];
        #pragma unroll
        for (int t = 0; t < 4; t++) {
            int row = t * 16 + cl;
            int sw = cl & 7;
            short8 bk0 = *reinterpret_cast<const short8*>(&Ktile[buf][row][(part ^ sw) * 8]);
            short8 bk1 = *reinterpret_cast<const short8*>(&Ktile[buf][row][((part + 4) ^ sw) * 8]);
            s[t] = __builtin_amdgcn_mfma_f32_16x16x32_bf16(aq0, bk0, zz, 0, 0, 0);
            s[t] = __builtin_amdgcn_mfma_f32_16x16x32_bf16(aq1, bk1, s[t], 0, 0, 0);
        }
        // ---- P = exp(S*scale); row-sum partials; stage D->A layout in pbuf
        #pragma unroll
        for (int t = 0; t < 4; t++)
            #pragma unroll
            for (int j = 0; j < 4; j++) {
                float e = exp2f(s[t][j] * SCALE_L2E);
                es[j] += e;
                pbuf[wid][r0 + j][t * 16 + cl] = f2bf(e);
            }
        short8 pa0 = *reinterpret_cast<const short8*>(&pbuf[wid][cl][ko]);
        short8 pa1 = *reinterpret_cast<const short8*>(&pbuf[wid][cl][32 + ko]);
        // ---- PV from swizzled V tile
        #pragma unroll
        for (int ct = 0; ct < 4; ct++) {
            int row = ct * 16 + cl;
            int sw = cl & 7;
            short8 bv0 = *reinterpret_cast<const short8*>(&Vtile[buf][row][(part ^ sw) * 8]);
            short8 bv1 = *reinterpret_cast<const short8*>(&Vtile[buf][row][((part + 4) ^ sw) * 8]);
            oacc[ct] = __builtin_amdgcn_mfma_f32_16x16x32_bf16(pa0, bv0, oacc[ct], 0, 0, 0);
            oacc[ct] = __builtin_amdgcn_mfma_f32_16x16x32_bf16(pa1, bv1, oacc[ct], 0, 0, 0);
        }
        __syncthreads();   // drains next-tile staging + protects buf swap
        buf ^= 1;
    }

    // row-sum reduce across the 16-lane column groups
    #pragma unroll
    for (int off = 1; off < 16; off <<= 1)
        #pragma unroll
        for (int j = 0; j < 4; j++) es[j] += __shfl_xor(es[j], off);
    float ri[4];
    #pragma unroll
    for (int j = 0; j < 4; j++) ri[j] = 1.f / es[j];

    // epilogue: normalize, add rank-1 cross term, transpose via pbuf, 16B stores
    const float* o2b = o2 + bh * 64;
    #pragma unroll
    for (int ct = 0; ct < 4; ct++) {
        float o2v = o2b[ct * 16 + cl];
        #pragma unroll
        for (int j = 0; j < 4; j++)
            pbuf[wid][r0 + j][ct * 16 + cl] = f2bf(oacc[ct][j] * ri[j] + o2v);
    }
    short8 w0 = *reinterpret_cast<const short8*>(&pbuf[wid][cl][part * 16]);
    short8 w1 = *reinterpret_cast<const short8*>(&pbuf[wid][cl][part * 16 + 8]);
    unsigned short* dst = AO + ((size_t)b * NHW + n0 + cl) * NC + h * 64 + part * 16;
    *reinterpret_cast<short8*>(dst)     = w0;
    *reinterpret_cast<short8*>(dst + 8) = w1;
}

// ---------------------------------------------------------------- launcher

extern "C" void kernel_launch(void* const* d_in, const int* in_sizes, int n_in,
                              void* d_out, int out_size, void* d_ws, size_t ws_size,
                              hipStream_t stream) {
    const float* x    = (const float*)d_in[0];
    const float* t    = (const float*)d_in[1];
    const float* Wk   = (const float*)d_in[2];
    const float* Wq   = (const float*)d_in[3];
    const float* Wt_w = (const float*)d_in[4];
    const float* Wt_b = (const float*)d_in[5];
    const float* Wm   = (const float*)d_in[6];
    const float* Wv   = (const float*)d_in[7];
    const float* Wr_w = (const float*)d_in[8];
    const float* Wr_b = (const float*)d_in[9];
    float* out = (float*)d_out;
    char* ws = (char*)d_ws;

    const size_t SZ_ACT = (size_t)NB * NHW * NC * 2;   // 9437184 bytes
    unsigned short* xT    = (unsigned short*)(ws);
    unsigned short* Wqkm  = (unsigned short*)(ws + 9437184);
    unsigned short* Wv_bf = (unsigned short*)(ws + 11010048);
    unsigned short* Wr_bf = (unsigned short*)(ws + 11534336);
    float*          tm     = (float*)(ws + 12058624);
    float*          tmerge = (float*)(ws + 12091392);
    unsigned short* QT    = (unsigned short*)(ws + 12124160);
    unsigned short* KT    = (unsigned short*)(ws + 21561344);
    unsigned short* vlT   = (unsigned short*)(ws + 30998528);
    unsigned short* Vv    = (unsigned short*)(ws + 40435712);
    float*          o2    = (float*)(ws + 49872896);
    unsigned short* AO    = xT;   // xT is dead after k_cross_o2; alias for AO
    (void)SZ_ACT; (void)in_sizes; (void)n_in; (void)out_size; (void)ws_size;

    k_prep_weights<<<5120, 256, 0, stream>>>(Wq, Wk, Wm, Wv, Wr_w, Wqkm, Wv_bf, Wr_bf);
    k_prep_xT<<<dim3(18, 16, 16), dim3(32, 8), 0, stream>>>(x, xT);
    k_prep_t<<<dim3(16, 4), 256, 0, stream>>>(t, Wt_w, Wt_b, Wm, tm, tmerge);
    k_gemm_qkm<<<dim3(54, 16), 256, 0, stream>>>(Wqkm, xT, tmerge, QT, KT, vlT);
    k_gemm_v<<<dim3(18, 16), 256, 0, stream>>>(Wv_bf, vlT, Vv);
    k_cross_o2<<<128, 256, 0, stream>>>(xT, Vv, tm, o2);
    k_attn<<<1152, 256, 0, stream>>>(QT, KT, Vv, o2, AO);
    k_gemm_final<<<dim3(18, 16), 256, 0, stream>>>(Wr_bf, AO, Wr_b, out);
}

// Round 8
// 124.726 us; speedup vs baseline: 2.4777x; 1.6698x over previous
//
#include <hip/hip_runtime.h>
#include <cstdint>
#include <cstddef>

#define NB    16
#define NC    512
#define NHW   576
#define NTF   512
#define NHEAD 8
#define NCPH  64
#define NTOT  9216                        // NB * NHW, flattened n dimension
#define ATT_SCALE 0.125f
#define SCALE_L2E 0.18033688011112042f   // 0.125 * log2(e)

typedef float  floatx4 __attribute__((ext_vector_type(4)));
typedef short  short8  __attribute__((ext_vector_type(8)));
typedef unsigned short ushortx4 __attribute__((ext_vector_type(4)));

__device__ __forceinline__ unsigned short f2bf(float f) {
    unsigned int u = __float_as_uint(f);
    u += 0x7fffu + ((u >> 16) & 1u);
    return (unsigned short)(u >> 16);
}
__device__ __forceinline__ float bf2f(unsigned short h) {
    return __uint_as_float(((unsigned int)h) << 16);
}

// ---------------------------------------------------------------- prep kernels

__global__ void k_prep_weights(const float* __restrict__ Wq, const float* __restrict__ Wk,
                               const float* __restrict__ Wm, const float* __restrict__ Wv,
                               const float* __restrict__ Wr,
                               unsigned short* __restrict__ Wqkm,
                               unsigned short* __restrict__ Wv_bf,
                               unsigned short* __restrict__ Wr_bf) {
    int i = blockIdx.x * 256 + threadIdx.x;
    if (i < 1536 * 512) {
        int r = i >> 9, c = i & 511;
        float v;
        if (r < 512)       v = Wq[r * 512 + c];
        else if (r < 1024) v = Wk[(r - 512) * 512 + c];
        else               v = Wm[(size_t)(r - 1024) * 1024 + c];
        Wqkm[i] = f2bf(v);
    } else {
        int j = i - 1536 * 512;
        if (j < 512 * 512) Wv_bf[j] = f2bf(Wv[j]);
        else               Wr_bf[j - 512 * 512] = f2bf(Wr[j - 512 * 512]);
    }
}

// xT[b][p][c] = bf16(x[b][c][p])   (tiled 32x32 transpose) -> flat [n][c]
__global__ void k_prep_xT(const float* __restrict__ x, unsigned short* __restrict__ xT) {
    __shared__ float tile[32][33];
    int b  = blockIdx.z;
    int p0 = blockIdx.x * 32, c0 = blockIdx.y * 32;
    int tx = threadIdx.x, ty = threadIdx.y;           // (32, 8)
    const float* xb = x + (size_t)b * NC * NHW;
    #pragma unroll
    for (int k = 0; k < 4; k++)
        tile[ty + k * 8][tx] = xb[(size_t)(c0 + ty + k * 8) * NHW + p0 + tx];
    __syncthreads();
    unsigned short* xTb = xT + (size_t)b * NHW * NC;
    #pragma unroll
    for (int k = 0; k < 4; k++)
        xTb[(size_t)(p0 + ty + k * 8) * NC + c0 + tx] = f2bf(tile[tx][ty + k * 8]);
}

// tm[b][o] = dot(Wt_w[o], t[b]) + Wt_b[o];  tmerge[b][o] = dot(Wm[o][512:], t[b])
__global__ void k_prep_t(const float* __restrict__ t, const float* __restrict__ Wt_w,
                         const float* __restrict__ Wt_b, const float* __restrict__ Wm,
                         float* __restrict__ tm, float* __restrict__ tmerge) {
    __shared__ float ts[512];
    int b = blockIdx.x;
    int tid = threadIdx.x;
    ts[tid]       = t[b * 512 + tid];
    ts[tid + 256] = t[b * 512 + tid + 256];
    __syncthreads();
    int oo = blockIdx.y * 256 + tid;
    const float* Wrow = (oo < 512) ? (Wt_w + (size_t)oo * 512)
                                   : (Wm + (size_t)(oo - 512) * 1024 + 512);
    float acc = 0.f;
    #pragma unroll 4
    for (int c = 0; c < 512; c += 4) {
        float4 w = *reinterpret_cast<const float4*>(Wrow + c);
        acc += w.x * ts[c] + w.y * ts[c + 1] + w.z * ts[c + 2] + w.w * ts[c + 3];
    }
    if (oo < 512) tm[b * 512 + oo] = acc + Wt_b[oo];
    else          tmerge[b * 512 + (oo - 512)] = acc;
}

// ---------------------------------------------------------------- 128x128 LDS-staged GEMM core
// A: [M][512] bf16 K-contig; B: [N][512] bf16 K-contig (flat n). Tile 128x128,
// 4 waves 2x2 (wave = 64x64), BK=64, double-buffered LDS via global_load_lds w16.
// T2 XOR swizzle: source col16 pre-swizzled with row&7; reads apply same XOR.

__device__ __forceinline__ void g128_stage(const unsigned short* __restrict__ src,  // + row0*NC + k0
                                           unsigned short* lds, int tid) {
    int row  = tid >> 3;                         // 0..31
    int slot = (tid & 7) ^ (row & 7);            // pre-swizzled source 16B slot
    #pragma unroll
    for (int i = 0; i < 4; i++) {
        __builtin_amdgcn_global_load_lds(
            (const __attribute__((address_space(1))) unsigned int*)(src + (size_t)(32 * i + row) * NC + slot * 8),
            (__attribute__((address_space(3))) unsigned int*)(lds + i * 2048 + tid * 8), 16, 0, 0);
    }
}

// fills acc[4][4] (wave's 64x64: acc[i][j], i = m-frag, j = n-frag)
__device__ __forceinline__ void g128_main(const unsigned short* __restrict__ Asrc,   // + m0*NC
                                          const unsigned short* __restrict__ Bsrc,   // + n0*NC
                                          unsigned short (*At)[8192], unsigned short (*Bt)[8192],
                                          int tid, int lane, int wr, int wc,
                                          floatx4 (&acc)[4][4]) {
    int cl = lane & 15, hi = lane >> 4, sx = cl & 7;

    g128_stage(Asrc, At[0], tid);
    g128_stage(Bsrc, Bt[0], tid);
    __syncthreads();

    int buf = 0;
    for (int ks = 0; ks < 8; ks++) {
        if (ks < 7) {
            g128_stage(Asrc + (ks + 1) * 64, At[buf ^ 1], tid);
            g128_stage(Bsrc + (ks + 1) * 64, Bt[buf ^ 1], tid);
        }
        #pragma unroll
        for (int kk = 0; kk < 2; kk++) {
            int sl = ((kk << 2) + hi) ^ sx;      // physical 16B slot
            short8 a[4], bb[4];
            #pragma unroll
            for (int i = 0; i < 4; i++)
                a[i] = *reinterpret_cast<const short8*>(&At[buf][(wr * 64 + i * 16 + cl) * 64 + sl * 8]);
            #pragma unroll
            for (int j = 0; j < 4; j++)
                bb[j] = *reinterpret_cast<const short8*>(&Bt[buf][(wc * 64 + j * 16 + cl) * 64 + sl * 8]);
            #pragma unroll
            for (int i = 0; i < 4; i++)
                #pragma unroll
                for (int j = 0; j < 4; j++)
                    acc[i][j] = __builtin_amdgcn_mfma_f32_16x16x32_bf16(a[i], bb[j], acc[i][j], 0, 0, 0);
        }
        __syncthreads();
        buf ^= 1;
    }
}

// Y = Wqkm @ xT^T -> QT/KT/vlT transposed [n][o_local], vl gets +tmerge.
// grid 864: bid = xcd + 8*slot; slot = m*9 + nl; ntile = xcd*9 + nl  (n-slice per XCD)
__global__ void k_gemm_qkm(const unsigned short* __restrict__ Wqkm,
                           const unsigned short* __restrict__ xT,
                           const float* __restrict__ tmerge,
                           unsigned short* __restrict__ QT,
                           unsigned short* __restrict__ KT,
                           unsigned short* __restrict__ vlT) {
    __shared__ unsigned short At[2][8192], Bt[2][8192];
    int tid = threadIdx.x, lane = tid & 63, wid = tid >> 6;
    int wr = wid >> 1, wc = wid & 1;
    int bid = blockIdx.x;
    int xcd = bid & 7, slot = bid >> 3;          // slot 0..107
    int m = slot / 9, nl = slot % 9;
    int n0 = (xcd * 9 + nl) * 128;
    int o0 = m * 128;

    floatx4 acc[4][4];
    floatx4 zz = {0.f, 0.f, 0.f, 0.f};
    #pragma unroll
    for (int i = 0; i < 4; i++)
        #pragma unroll
        for (int j = 0; j < 4; j++) acc[i][j] = zz;

    g128_main(Wqkm + (size_t)o0 * NC, xT + (size_t)n0 * NC, At, Bt, tid, lane, wr, wc, acc);

    unsigned short* Yt;
    bool addm = false;
    if (m < 4)      Yt = QT;
    else if (m < 8) Yt = KT;
    else          { Yt = vlT; addm = true; }
    int ob = (m & 3) * 128 + wr * 64;            // o_local base for this wave

    int cl = lane & 15, r0 = (lane >> 4) * 4;
    #pragma unroll
    for (int i = 0; i < 4; i++) {
        int ol = ob + i * 16 + r0;
        #pragma unroll
        for (int jn = 0; jn < 4; jn++) {
            int n = n0 + wc * 64 + jn * 16 + cl;
            float a0 = 0.f, a1 = 0.f, a2 = 0.f, a3 = 0.f;
            if (addm) {
                int b = n / NHW;
                float4 tv = *reinterpret_cast<const float4*>(tmerge + b * NC + ol);
                a0 = tv.x; a1 = tv.y; a2 = tv.z; a3 = tv.w;
            }
            ushortx4 pk;
            pk[0] = f2bf(acc[i][jn][0] + a0);
            pk[1] = f2bf(acc[i][jn][1] + a1);
            pk[2] = f2bf(acc[i][jn][2] + a2);
            pk[3] = f2bf(acc[i][jn][3] + a3);
            *reinterpret_cast<ushortx4*>(Yt + (size_t)n * NC + ol) = pk;
        }
    }
}

// V = Wv @ vl -> natural V[b][c][p] bf16 (scatter epilogue).
// grid 288: slot = bid>>3 (0..35); m = slot/9, nl = slot%9, ntile = xcd*9+nl
__global__ void k_gemm_v(const unsigned short* __restrict__ Wv_bf,
                         const unsigned short* __restrict__ vlT,
                         unsigned short* __restrict__ V) {
    __shared__ unsigned short At[2][8192], Bt[2][8192];
    int tid = threadIdx.x, lane = tid & 63, wid = tid >> 6;
    int wr = wid >> 1, wc = wid & 1;
    int bid = blockIdx.x;
    int xcd = bid & 7, slot = bid >> 3;
    int m = slot / 9, nl = slot % 9;
    int n0 = (xcd * 9 + nl) * 128;
    int o0 = m * 128;

    floatx4 acc[4][4];
    floatx4 zz = {0.f, 0.f, 0.f, 0.f};
    #pragma unroll
    for (int i = 0; i < 4; i++)
        #pragma unroll
        for (int j = 0; j < 4; j++) acc[i][j] = zz;

    g128_main(Wv_bf + (size_t)o0 * NC, vlT + (size_t)n0 * NC, At, Bt, tid, lane, wr, wc, acc);

    int cl = lane & 15, r0 = (lane >> 4) * 4;
    #pragma unroll
    for (int i = 0; i < 4; i++)
        #pragma unroll
        for (int jn = 0; jn < 4; jn++) {
            int n = n0 + wc * 64 + jn * 16 + cl;
            int b = n / NHW, p = n - b * NHW;
            #pragma unroll
            for (int j = 0; j < 4; j++) {
                int c = o0 + wr * 64 + i * 16 + r0 + j;
                V[((size_t)b * NC + c) * NHW + p] = f2bf(acc[i][jn][j]);
            }
        }
}

// out = Wr @ AO^T + Wr_b -> natural f32 [b][o][p] (scatter epilogue).
__global__ void k_gemm_final(const unsigned short* __restrict__ Wr_bf,
                             const unsigned short* __restrict__ AO,
                             const float* __restrict__ Wr_b,
                             float* __restrict__ out) {
    __shared__ unsigned short At[2][8192], Bt[2][8192];
    int tid = threadIdx.x, lane = tid & 63, wid = tid >> 6;
    int wr = wid >> 1, wc = wid & 1;
    int bid = blockIdx.x;
    int xcd = bid & 7, slot = bid >> 3;
    int m = slot / 9, nl = slot % 9;
    int n0 = (xcd * 9 + nl) * 128;
    int o0 = m * 128;

    floatx4 acc[4][4];
    floatx4 zz = {0.f, 0.f, 0.f, 0.f};
    #pragma unroll
    for (int i = 0; i < 4; i++)
        #pragma unroll
        for (int j = 0; j < 4; j++) acc[i][j] = zz;

    g128_main(Wr_bf + (size_t)o0 * NC, AO + (size_t)n0 * NC, At, Bt, tid, lane, wr, wc, acc);

    int cl = lane & 15, r0 = (lane >> 4) * 4;
    #pragma unroll
    for (int i = 0; i < 4; i++) {
        float4 bv = *reinterpret_cast<const float4*>(Wr_b + o0 + wr * 64 + i * 16 + r0);
        float bias[4] = {bv.x, bv.y, bv.z, bv.w};
        #pragma unroll
        for (int jn = 0; jn < 4; jn++) {
            int n = n0 + wc * 64 + jn * 16 + cl;
            int b = n / NHW, p = n - b * NHW;
            #pragma unroll
            for (int j = 0; j < 4; j++) {
                int c = o0 + wr * 64 + i * 16 + r0 + j;
                out[((size_t)b * NC + c) * NHW + p] = acc[i][jn][j] + bias[j];
            }
        }
    }
}

// ---------------------------------------------------------------- cross + o2

__global__ void k_cross_o2(const unsigned short* __restrict__ xT,
                           const unsigned short* __restrict__ V,
                           const float* __restrict__ tm,
                           float* __restrict__ o2) {
    __shared__ float tms[64];
    __shared__ float ss[576];
    __shared__ float red[8];
    __shared__ float part[4][64];
    int bh = blockIdx.x;
    int b = bh >> 3, h = bh & 7;
    int tid = threadIdx.x;

    if (tid < 64) tms[tid] = tm[b * 512 + h * 64 + tid];
    __syncthreads();

    for (int m = tid; m < 576; m += 256) {
        const short8* xr8 = reinterpret_cast<const short8*>(xT + ((size_t)b * NHW + m) * NC + h * 64);
        float acc = 0.f;
        #pragma unroll
        for (int cc = 0; cc < 8; cc++) {
            short8 v8 = xr8[cc];
            #pragma unroll
            for (int q = 0; q < 8; q++)
                acc += bf2f((unsigned short)v8[q]) * tms[cc * 8 + q];
        }
        ss[m] = acc * ATT_SCALE;
    }
    __syncthreads();

    float pmax = -3e38f;
    for (int m = tid; m < 576; m += 256) pmax = fmaxf(pmax, ss[m]);
    #pragma unroll
    for (int off = 32; off; off >>= 1) pmax = fmaxf(pmax, __shfl_xor(pmax, off));
    if ((tid & 63) == 0) red[tid >> 6] = pmax;
    __syncthreads();
    float mx = fmaxf(fmaxf(red[0], red[1]), fmaxf(red[2], red[3]));

    float psum = 0.f;
    for (int m = tid; m < 576; m += 256) {
        float e = __expf(ss[m] - mx);
        ss[m] = e;
        psum += e;
    }
    #pragma unroll
    for (int off = 32; off; off >>= 1) psum += __shfl_xor(psum, off);
    if ((tid & 63) == 0) red[4 + (tid >> 6)] = psum;
    __syncthreads();
    float inv = 1.f / (red[4] + red[5] + red[6] + red[7]);

    int c = tid & 63, seg = tid >> 6;
    const unsigned short* vr = V + ((size_t)b * NC + h * 64 + c) * NHW;
    float pa = 0.f;
    for (int m = seg * 144; m < seg * 144 + 144; m++) pa += bf2f(vr[m]) * ss[m];
    part[seg][c] = pa;
    __syncthreads();
    if (tid < 64)
        o2[(b * 8 + h) * 64 + tid] =
            (part[0][tid] + part[1][tid] + part[2][tid] + part[3][tid]) * inv;
}

// ---------------------------------------------------------------- attention core
// (v4 structure, unchanged: cooperative-LDS 2-phase pipeline, XCD-grouped)

__global__ void k_attn(const unsigned short* __restrict__ QT,
                       const unsigned short* __restrict__ KT,
                       const unsigned short* __restrict__ V,
                       const float* __restrict__ o2,
                       unsigned short* __restrict__ AO) {
    __shared__ unsigned short Ktile[2][64][64];
    __shared__ unsigned short Vtile[2][64][64];
    __shared__ unsigned short pbuf[4][16][88];
    int tid  = threadIdx.x;
    int lane = tid & 63, wid = tid >> 6;

    int bid  = blockIdx.x;
    int xcd  = bid & 7;
    int slot = bid >> 3;
    int bh   = xcd * 16 + slot / 9;
    int qt   = slot % 9;
    int b = bh >> 3, h = bh & 7;
    int n0 = qt * 64 + wid * 16;
    int cl = lane & 15;
    int r0 = (lane >> 4) * 4;
    int part = lane >> 4;
    int ko = part * 8;

    const unsigned short* Qb = QT + ((size_t)b * NHW + n0) * NC + h * 64;
    const unsigned short* Kb = KT + (size_t)b * NHW * NC + h * 64;
    const unsigned short* Vb = V  + ((size_t)b * NC + h * 64) * NHW;

    short8 aq0 = *reinterpret_cast<const short8*>(Qb + (size_t)cl * NC + ko);
    short8 aq1 = *reinterpret_cast<const short8*>(Qb + (size_t)cl * NC + 32 + ko);

    int srow = lane >> 3;
    int scol = (lane & 7) ^ srow;

    floatx4 zz = {0.f, 0.f, 0.f, 0.f};
    floatx4 oacc[4] = {zz, zz, zz, zz};
    float es[4] = {0.f, 0.f, 0.f, 0.f};

    {
        const unsigned short* ks = Kb + (size_t)(wid * 16 + srow) * NC + scol * 8;
        const unsigned short* vs = Vb + (size_t)(wid * 16 + srow) * NHW + scol * 8;
        #pragma unroll
        for (int i = 0; i < 2; i++) {
            __builtin_amdgcn_global_load_lds(
                (const __attribute__((address_space(1))) unsigned int*)(ks + (size_t)i * 8 * NC),
                (__attribute__((address_space(3))) unsigned int*)&Ktile[0][wid * 16 + i * 8][0], 16, 0, 0);
            __builtin_amdgcn_global_load_lds(
                (const __attribute__((address_space(1))) unsigned int*)(vs + (size_t)i * 8 * NHW),
                (__attribute__((address_space(3))) unsigned int*)&Vtile[0][wid * 16 + i * 8][0], 16, 0, 0);
        }
    }
    __syncthreads();

    int buf = 0;
    for (int chk = 0; chk < 9; chk++) {
        int m0 = chk * 64;
        if (chk < 8) {
            const unsigned short* ks = Kb + (size_t)(m0 + 64 + wid * 16 + srow) * NC + scol * 8;
            const unsigned short* vs = Vb + (size_t)(wid * 16 + srow) * NHW + (m0 + 64) + scol * 8;
            #pragma unroll
            for (int i = 0; i < 2; i++) {
                __builtin_amdgcn_global_load_lds(
                    (const __attribute__((address_space(1))) unsigned int*)(ks + (size_t)i * 8 * NC),
                    (__attribute__((address_space(3))) unsigned int*)&Ktile[buf ^ 1][wid * 16 + i * 8][0], 16, 0, 0);
                __builtin_amdgcn_global_load_lds(
                    (const __attribute__((address_space(1))) unsigned int*)(vs + (size_t)i * 8 * NHW),
                    (__attribute__((address_space(3))) unsigned int*)&Vtile[buf ^ 1][wid * 16 + i * 8][0], 16, 0, 0);
            }
        }

        floatx4 s[4];
        #pragma unroll
        for (int t = 0; t < 4; t++) {
            int row = t * 16 + cl;
            int sw = cl & 7;
            short8 bk0 = *reinterpret_cast<const short8*>(&Ktile[buf][row][(part ^ sw) * 8]);
            short8 bk1 = *reinterpret_cast<const short8*>(&Ktile[buf][row][((part + 4) ^ sw) * 8]);
            s[t] = __builtin_amdgcn_mfma_f32_16x16x32_bf16(aq0, bk0, zz, 0, 0, 0);
            s[t] = __builtin_amdgcn_mfma_f32_16x16x32_bf16(aq1, bk1, s[t], 0, 0, 0);
        }
        #pragma unroll
        for (int t = 0; t < 4; t++)
            #pragma unroll
            for (int j = 0; j < 4; j++) {
                float e = exp2f(s[t][j] * SCALE_L2E);
                es[j] += e;
                pbuf[wid][r0 + j][t * 16 + cl] = f2bf(e);
            }
        short8 pa0 = *reinterpret_cast<const short8*>(&pbuf[wid][cl][ko]);
        short8 pa1 = *reinterpret_cast<const short8*>(&pbuf[wid][cl][32 + ko]);
        #pragma unroll
        for (int ct = 0; ct < 4; ct++) {
            int row = ct * 16 + cl;
            int sw = cl & 7;
            short8 bv0 = *reinterpret_cast<const short8*>(&Vtile[buf][row][(part ^ sw) * 8]);
            short8 bv1 = *reinterpret_cast<const short8*>(&Vtile[buf][row][((part + 4) ^ sw) * 8]);
            oacc[ct] = __builtin_amdgcn_mfma_f32_16x16x32_bf16(pa0, bv0, oacc[ct], 0, 0, 0);
            oacc[ct] = __builtin_amdgcn_mfma_f32_16x16x32_bf16(pa1, bv1, oacc[ct], 0, 0, 0);
        }
        __syncthreads();
        buf ^= 1;
    }

    #pragma unroll
    for (int off = 1; off < 16; off <<= 1)
        #pragma unroll
        for (int j = 0; j < 4; j++) es[j] += __shfl_xor(es[j], off);
    float ri[4];
    #pragma unroll
    for (int j = 0; j < 4; j++) ri[j] = 1.f / es[j];

    const float* o2b = o2 + bh * 64;
    #pragma unroll
    for (int ct = 0; ct < 4; ct++) {
        float o2v = o2b[ct * 16 + cl];
        #pragma unroll
        for (int j = 0; j < 4; j++)
            pbuf[wid][r0 + j][ct * 16 + cl] = f2bf(oacc[ct][j] * ri[j] + o2v);
    }
    short8 w0 = *reinterpret_cast<const short8*>(&pbuf[wid][cl][part * 16]);
    short8 w1 = *reinterpret_cast<const short8*>(&pbuf[wid][cl][part * 16 + 8]);
    unsigned short* dst = AO + ((size_t)b * NHW + n0 + cl) * NC + h * 64 + part * 16;
    *reinterpret_cast<short8*>(dst)     = w0;
    *reinterpret_cast<short8*>(dst + 8) = w1;
}

// ---------------------------------------------------------------- launcher

extern "C" void kernel_launch(void* const* d_in, const int* in_sizes, int n_in,
                              void* d_out, int out_size, void* d_ws, size_t ws_size,
                              hipStream_t stream) {
    const float* x    = (const float*)d_in[0];
    const float* t    = (const float*)d_in[1];
    const float* Wk   = (const float*)d_in[2];
    const float* Wq   = (const float*)d_in[3];
    const float* Wt_w = (const float*)d_in[4];
    const float* Wt_b = (const float*)d_in[5];
    const float* Wm   = (const float*)d_in[6];
    const float* Wv   = (const float*)d_in[7];
    const float* Wr_w = (const float*)d_in[8];
    const float* Wr_b = (const float*)d_in[9];
    float* out = (float*)d_out;
    char* ws = (char*)d_ws;

    unsigned short* xT    = (unsigned short*)(ws);
    unsigned short* Wqkm  = (unsigned short*)(ws + 9437184);
    unsigned short* Wv_bf = (unsigned short*)(ws + 11010048);
    unsigned short* Wr_bf = (unsigned short*)(ws + 11534336);
    float*          tm     = (float*)(ws + 12058624);
    float*          tmerge = (float*)(ws + 12091392);
    unsigned short* QT    = (unsigned short*)(ws + 12124160);
    unsigned short* KT    = (unsigned short*)(ws + 21561344);
    unsigned short* vlT   = (unsigned short*)(ws + 30998528);
    unsigned short* Vv    = (unsigned short*)(ws + 40435712);
    float*          o2    = (float*)(ws + 49872896);
    unsigned short* AO    = xT;   // xT is dead after k_cross_o2; alias for AO
    (void)in_sizes; (void)n_in; (void)out_size; (void)ws_size;

    k_prep_weights<<<5120, 256, 0, stream>>>(Wq, Wk, Wm, Wv, Wr_w, Wqkm, Wv_bf, Wr_bf);
    k_prep_xT<<<dim3(18, 16, 16), dim3(32, 8), 0, stream>>>(x, xT);
    k_prep_t<<<dim3(16, 4), 256, 0, stream>>>(t, Wt_w, Wt_b, Wm, tm, tmerge);
    k_gemm_qkm<<<864, 256, 0, stream>>>(Wqkm, xT, tmerge, QT, KT, vlT);
    k_gemm_v<<<288, 256, 0, stream>>>(Wv_bf, vlT, Vv);
    k_cross_o2<<<128, 256, 0, stream>>>(xT, Vv, tm, o2);
    k_attn<<<1152, 256, 0, stream>>>(QT, KT, Vv, o2, AO);
    k_gemm_final<<<288, 256, 0, stream>>>(Wr_bf, AO, Wr_b, out);
}